// Round 5
// baseline (206.742 us; speedup 1.0000x reference)
//
#include <hip/hip_runtime.h>
#include <cstdint>

#define CD 64
#define HWD 589824
#define NSAMP 8192
#define STILES (NSAMP / 32)         // 256
#define PAD_TAU 0.25f
#define NTILE 32
#define TILES (HWD / NTILE)         // 18432
#define K1_BLOCKS 1536
#define K1_WAVES (K1_BLOCKS * 4)    // 6144
#define TPW (TILES / K1_WAVES)      // 3
#define W2 (K1_WAVES * 2)           // 12288 cell rows
#define NLIST 128                   // k2a waves (= 32 blocks * 4)
#define K2A_BLOCKS (NLIST / 4)
#define RPW (W2 / NLIST)            // 96 rows per k2a wave
#define FMAXV 3.402823466e+38f

typedef float f32x16 __attribute__((ext_vector_type(16)));
typedef short bf16x8 __attribute__((ext_vector_type(8)));

__device__ __forceinline__ short f2bf(float f) {
    unsigned u = __float_as_uint(f);
    u = u + 0x7FFFu + ((u >> 16) & 1u);   // RNE
    return (short)(u >> 16);
}

// exact 16-smallest screen (static indexing only)
#define SCREEN(d, lst, cm)                                                  \
    if ((d) < (cm)) {                                                       \
        bool rep = false;                                                   \
        _Pragma("unroll")                                                   \
        for (int j = 0; j < 16; ++j)                                        \
            if (!rep && lst[j] == (cm)) { lst[j] = (d); rep = true; }       \
        cm = lst[0];                                                        \
        _Pragma("unroll")                                                   \
        for (int j = 1; j < 16; ++j) cm = fmaxf(cm, lst[j]);                \
    }

// Shared tile engine: d(p, n0+.) for 32 columns x 64 p.
__device__ __forceinline__ void tile_dist(
    const float* __restrict__ fp,          // f2 + n0 + l31
    const bf16x8* __restrict__ sf0, const bf16x8* __restrict__ sf1,
    int lh, f32x16& acc0, f32x16& acc1, float& fs)
{
    fs = 0.f;
#pragma unroll
    for (int i = 0; i < 16; ++i) { acc0[i] = 0.f; acc1[i] = 0.f; }
#pragma unroll
    for (int ks = 0; ks < 4; ++ks) {
        float av[8];
#pragma unroll
        for (int j = 0; j < 8; ++j)
            av[j] = fp[(long)(16 * ks + 8 * lh + j) * HWD];
        bf16x8 af;
#pragma unroll
        for (int j = 0; j < 8; ++j) {
            fs += av[j] * av[j];
            af[j] = f2bf(av[j]);
        }
        acc0 = __builtin_amdgcn_mfma_f32_32x32x16_bf16(af, sf0[ks], acc0, 0, 0, 0);
        acc1 = __builtin_amdgcn_mfma_f32_32x32x16_bf16(af, sf1[ks], acc1, 0, 0, 0);
    }
    fs += __shfl_xor(fs, 32);   // combine k-halves (same column n)
}

// k_pack: one wave packs sel bf16 B-fragments + ||sel||^2.
__global__ void k_pack(const float* __restrict__ f1, const int* __restrict__ nidx,
                       bf16x8* __restrict__ selpack, float* __restrict__ sel2p)
{
    const int lane = threadIdx.x;          // 64 threads
    const int l31 = lane & 31, lh = lane >> 5;
#pragma unroll
    for (int b = 0; b < 2; ++b) {
        long colb = (long)nidx[l31 + 32 * b];
        float s2 = 0.f;
#pragma unroll
        for (int ks = 0; ks < 4; ++ks) {
            bf16x8 fr;
#pragma unroll
            for (int j = 0; j < 8; ++j) {
                float v = f1[(long)(16 * ks + 8 * lh + j) * HWD + colb];
                s2 += v * v;
                fr[j] = f2bf(v);
            }
            selpack[(b * 4 + ks) * 64 + lane] = fr;
        }
        s2 += __shfl_xor(s2, 32);
        sel2p[b * 64 + lane] = s2;
    }
}

// k0a: 256 one-wave blocks over the first 8192 columns; writes dsT[n][p].
__global__ __launch_bounds__(64) void k0a_sample(
    const float* __restrict__ f2, const bf16x8* __restrict__ selpack,
    const float* __restrict__ sel2p, float* __restrict__ dsT)
{
    const int lane = threadIdx.x;
    const int l31 = lane & 31, lh = lane >> 5;
    const long n0 = (long)blockIdx.x * NTILE;

    bf16x8 sf0[4], sf1[4];
#pragma unroll
    for (int ks = 0; ks < 4; ++ks) {
        sf0[ks] = selpack[ks * 64 + lane];
        sf1[ks] = selpack[(4 + ks) * 64 + lane];
    }
    const float sel20 = sel2p[lane], sel21 = sel2p[64 + lane];

    f32x16 acc0, acc1; float fs;
    tile_dist(f2 + n0 + l31, sf0, sf1, lh, acc0, acc1, fs);

#pragma unroll
    for (int i = 0; i < 16; ++i) {
        int r = (i & 3) + 8 * (i >> 2) + 4 * lh;
        float fr2 = __shfl(fs, r);
        dsT[(n0 + r) * 64 + l31]      = fmaxf(sel20 + fr2 - 2.f * acc0[i], 0.f);
        dsT[(n0 + r) * 64 + 32 + l31] = fmaxf(sel21 + fr2 - 2.f * acc1[i], 0.f);
    }
}

// k0b: block p -> 16th smallest of dsT[:, p] + pad = tau[p].
__global__ __launch_bounds__(256) void k0b_tau(
    const float* __restrict__ dsT, float* __restrict__ tau)
{
    const int p = blockIdx.x;
    const int tid = threadIdx.x;
    const int lane = tid & 63, wid = tid >> 6;
    __shared__ unsigned long long wmin[4];

    float lst[16];
#pragma unroll
    for (int j = 0; j < 16; ++j) lst[j] = FMAXV;
    float cm = FMAXV;
#pragma unroll
    for (int c = 0; c < NSAMP / 256; ++c) {
        float d = dsT[(long)(c * 256 + tid) * 64 + p];
        SCREEN(d, lst, cm);
    }

    float last = 0.f;
    for (int r = 0; r < 16; ++r) {
        float mn = lst[0]; int a = 0;
#pragma unroll
        for (int j = 1; j < 16; ++j) if (lst[j] < mn) { mn = lst[j]; a = j; }
        unsigned long long key =
            ((unsigned long long)__float_as_uint(mn) << 32) | (unsigned)(tid * 16 + a);
#pragma unroll
        for (int off = 32; off; off >>= 1) {
            unsigned long long o = __shfl_xor(key, off);
            if (o < key) key = o;
        }
        if (lane == 0) wmin[wid] = key;
        __syncthreads();
        unsigned long long gk = wmin[0];
#pragma unroll
        for (int w = 1; w < 4; ++w) if (wmin[w] < gk) gk = wmin[w];
        last = __uint_as_float((unsigned)(gk >> 32));
        int slot = (int)(gk & 0xFFFFFFFFu);
        if ((slot >> 4) == tid) {
#pragma unroll
            for (int j = 0; j < 16; ++j) if (j == (slot & 15)) lst[j] = FMAXV;
        }
        __syncthreads();
    }
    if (tid == 0) tau[p] = last + PAD_TAU;
}

// K1: stream f2, MFMA distances, filter vs tau into dense FMAXV-filled float4
// cells surv4[row = gw*2+lh][col = p] (coalesced stores, no cnt, no atomics).
__global__ __launch_bounds__(256) void k1_dist(
    const float* __restrict__ f2, const bf16x8* __restrict__ selpack,
    const float* __restrict__ sel2p, const float* __restrict__ tau,
    float4* __restrict__ surv4)
{
    const int tid = threadIdx.x;
    const int lane = tid & 63, wid = tid >> 6;
    const int l31 = lane & 31, lh = lane >> 5;
    const int gw = blockIdx.x * 4 + wid;        // 0..6143

    bf16x8 sf0[4], sf1[4];
#pragma unroll
    for (int ks = 0; ks < 4; ++ks) {
        sf0[ks] = selpack[ks * 64 + lane];
        sf1[ks] = selpack[(4 + ks) * 64 + lane];
    }
    const float sel20 = sel2p[lane], sel21 = sel2p[64 + lane];
    const float tau0 = tau[l31], tau1 = tau[l31 + 32];

    float4 v0 = make_float4(FMAXV, FMAXV, FMAXV, FMAXV);
    float4 v1 = v0;
    unsigned c0 = 0, c1 = 0;

    for (int t = 0; t < TPW; ++t) {
        const long n0 = (long)(gw * TPW + t) * NTILE;
        f32x16 acc0, acc1; float fs;
        tile_dist(f2 + n0 + l31, sf0, sf1, lh, acc0, acc1, fs);

#pragma unroll
        for (int i = 0; i < 16; ++i) {
            int r = (i & 3) + 8 * (i >> 2) + 4 * lh;
            float fr2 = __shfl(fs, r);
            float d0 = fmaxf(sel20 + fr2 - 2.f * acc0[i], 0.f);
            if (d0 <= tau0) {
                if (c0 == 0) v0.x = d0; else if (c0 == 1) v0.y = d0;
                else if (c0 == 2) v0.z = d0; else if (c0 == 3) v0.w = d0;
                ++c0;
            }
            float d1 = fmaxf(sel21 + fr2 - 2.f * acc1[i], 0.f);
            if (d1 <= tau1) {
                if (c1 == 0) v1.x = d1; else if (c1 == 1) v1.y = d1;
                else if (c1 == 2) v1.z = d1; else if (c1 == 3) v1.w = d1;
                ++c1;
            }
        }
    }
    float4* srow = surv4 + ((long)gw * 2 + lh) * 64;
    srow[l31]      = v0;   // p = l31
    srow[l31 + 32] = v1;   // p = l31 + 32
}

// k2a: 32 blocks (128 waves). Wave reads 96 coalesced rows of surv4[W2][64];
// lane l screens column p=l into a register top-16. Emits cand2[p][wv][16].
__global__ __launch_bounds__(256) void k2a_screen(
    const float4* __restrict__ surv4, float* __restrict__ cand2)
{
    const int lane = threadIdx.x & 63;
    const int wv = blockIdx.x * 4 + (threadIdx.x >> 6);   // 0..127

    float lst[16];
#pragma unroll
    for (int j = 0; j < 16; ++j) lst[j] = FMAXV;
    float cm = FMAXV;

    const float4* base = surv4 + (long)wv * RPW * 64 + lane;
#pragma unroll 8
    for (int r = 0; r < RPW; ++r) {
        float4 v = base[r * 64];
        SCREEN(v.x, lst, cm);
        SCREEN(v.y, lst, cm);
        SCREEN(v.z, lst, cm);
        SCREEN(v.w, lst, cm);
    }

    float4* o = (float4*)(cand2 + ((long)lane * NLIST + wv) * 16);
#pragma unroll
    for (int q = 0; q < 4; ++q)
        o[q] = make_float4(lst[4*q], lst[4*q+1], lst[4*q+2], lst[4*q+3]);
}

// k2b: one wave per p. 2048 candidates -> exact top-16 -> sum.
__global__ __launch_bounds__(64) void k2b_select(
    const float* __restrict__ cand2, float* __restrict__ partial)
{
    const int p = blockIdx.x;
    const int lane = threadIdx.x;
    const float* base = cand2 + (long)p * NLIST * 16;

    float lst[16];
#pragma unroll
    for (int j = 0; j < 16; ++j) lst[j] = FMAXV;
    float cm = FMAXV;
#pragma unroll 4
    for (int k = 0; k < 32; ++k) {
        float d = base[k * 64 + lane];
        SCREEN(d, lst, cm);
    }

    float sum = 0.f;
    for (int r = 0; r < 16; ++r) {
        float mn = lst[0]; int a = 0;
#pragma unroll
        for (int j = 1; j < 16; ++j) if (lst[j] < mn) { mn = lst[j]; a = j; }
        unsigned long long key =
            ((unsigned long long)__float_as_uint(mn) << 32) | (unsigned)(lane * 16 + a);
#pragma unroll
        for (int off = 32; off; off >>= 1) {
            unsigned long long o = __shfl_xor(key, off);
            if (o < key) key = o;
        }
        sum += __uint_as_float((unsigned)(key >> 32));
        int slot = (int)(key & 0xFFFFFFFFu);
        if ((slot >> 4) == lane) {
#pragma unroll
            for (int j = 0; j < 16; ++j) if (j == (slot & 15)) lst[j] = FMAXV;
        }
    }
    if (lane == 0) partial[p] = sum;
}

__global__ void k3_final(const float* __restrict__ partial, float* __restrict__ out)
{
    float v = partial[threadIdx.x];   // 64 threads
#pragma unroll
    for (int off = 32; off; off >>= 1) v += __shfl_xor(v, off);
    if (threadIdx.x == 0) out[0] = -v / 1024.0f;
}

extern "C" void kernel_launch(void* const* d_in, const int* in_sizes, int n_in,
                              void* d_out, int out_size, void* d_ws, size_t ws_size,
                              hipStream_t stream)
{
    const float* f1   = (const float*)d_in[0];
    const float* f2   = (const float*)d_in[1];
    const int*   nidx = (const int*)d_in[3];     // negative_indices
    float* out = (float*)d_out;

    float4* surv4 = (float4*)d_ws;                       // 12288*64*16 B = 12.6 MB
    float*  dsT   = (float*)d_ws;                        // 2 MB, aliases surv4
                                                         // (consumed by k0b before k1)
    float*  cand2 = (float*)(surv4 + (long)W2 * 64);     // 64*128*16 fl = 512 KB
    bf16x8* selpack = (bf16x8*)(cand2 + (long)CD * NLIST * 16);   // 8 KB
    float*  sel2p = (float*)(selpack + 8 * 64);
    float*  tau   = sel2p + 128;
    float*  partial = tau + CD;

    k_pack    <<<1,          64, 0, stream>>>(f1, nidx, selpack, sel2p);
    k0a_sample<<<STILES,     64, 0, stream>>>(f2, selpack, sel2p, dsT);
    k0b_tau   <<<CD,        256, 0, stream>>>(dsT, tau);
    k1_dist   <<<K1_BLOCKS, 256, 0, stream>>>(f2, selpack, sel2p, tau, surv4);
    k2a_screen<<<K2A_BLOCKS,256, 0, stream>>>(surv4, cand2);
    k2b_select<<<CD,         64, 0, stream>>>(cand2, partial);
    k3_final  <<<1,          64, 0, stream>>>(partial, out);
}